// Round 1
// baseline (415.306 us; speedup 1.0000x reference)
//
#include <hip/hip_runtime.h>

// GCN layer: h = x @ W_conv; conv = D^-1/2 (A+I) D^-1/2 h + b_conv; out = conv @ W_lin + b_lin
// N=50000, E=800000, in_c=256, hid=128. All fp32.

#define N_NODES 50000
#define N_EDGES 800000
#define IN_C 256
#define HID 128

// workspace layout (bytes)
#define OFF_H    0UL          // 50000*128 f32 = 25,600,000
#define OFF_CONV 25600000UL   // 50000*128 f32 = 25,600,000
#define OFF_DEG  51200000UL   // 50000 i32
#define OFF_CNT  51400000UL   // 50000 i32
#define OFF_RP   51600000UL   // 50001 i32
#define OFF_DINV 51800064UL   // 50000 f32
#define OFF_CSR  52000064UL   // 800000 i32  (ends 55,200,064)

__global__ void deg_kernel(const int* __restrict__ dst, int* __restrict__ deg, int e) {
    int i = blockIdx.x * blockDim.x + threadIdx.x;
    if (i < e) atomicAdd(&deg[dst[i]], 1);
}

// single-block exclusive scan over n=50000 (chunk-per-thread + Hillis-Steele on chunk sums)
__global__ void scan_kernel(const int* __restrict__ deg, int* __restrict__ row_ptr, int n) {
    __shared__ int sums[1024];
    int tid = threadIdx.x;
    const int per = (n + 1023) / 1024;
    int start = tid * per;
    int end = min(start + per, n);
    int s = 0;
    for (int i = start; i < end; ++i) s += deg[i];
    sums[tid] = s;
    __syncthreads();
    for (int off = 1; off < 1024; off <<= 1) {
        int v = (tid >= off) ? sums[tid - off] : 0;
        __syncthreads();
        sums[tid] += v;
        __syncthreads();
    }
    int offset = (tid == 0) ? 0 : sums[tid - 1];
    for (int i = start; i < end; ++i) { row_ptr[i] = offset; offset += deg[i]; }
    if (tid == 1023) row_ptr[n] = offset;   // thread 1023's chunk is past n; offset == total
}

__global__ void dinv_kernel(const int* __restrict__ row_ptr, float* __restrict__ dinv, int n) {
    int i = blockIdx.x * blockDim.x + threadIdx.x;
    if (i < n) {
        int d = row_ptr[i + 1] - row_ptr[i] + 1;   // +1 self-loop
        dinv[i] = rsqrtf((float)d);
    }
}

__global__ void bucket_kernel(const int* __restrict__ src, const int* __restrict__ dst,
                              const int* __restrict__ row_ptr, int* __restrict__ cnt,
                              int* __restrict__ csr_src, int e) {
    int i = blockIdx.x * blockDim.x + threadIdx.x;
    if (i < e) {
        int d = dst[i];
        int slot = row_ptr[d] + atomicAdd(&cnt[d], 1);
        csr_src[slot] = src[i];
    }
}

// C[M,N] = A[M,K] @ B[K,N] (+bias). BM=64,BN=64,BK=32; 256 thr, 4x4/thread.
// Requires K%32==0, N%64==0 (holds: K in {256,128}, N in {128,256}).
#define BM 64
#define BN 64
#define BK 32
__global__ __launch_bounds__(256) void sgemm_kernel(
    const float* __restrict__ A, const float* __restrict__ B,
    const float* __restrict__ bias, float* __restrict__ C,
    int M, int N, int K)
{
    __shared__ float As[BK][BM + 4];   // transposed A tile, padded (16B-aligned rows)
    __shared__ float Bs[BK][BN];
    int tid = threadIdx.x;
    int block_row = blockIdx.x * BM;
    int block_col = blockIdx.y * BN;
    int tr = tid >> 4;          // 0..15 -> rows tr*4..tr*4+3
    int tc = tid & 15;          // 0..15 -> cols tc*4..tc*4+3
    int ar = tid >> 3;          // 0..31 A-staging row
    int ac = (tid & 7) << 2;    // A-staging col group
    int bkr = tid >> 4;         // 0..15 B-staging k row
    int bc = (tid & 15) << 2;   // B-staging col group
    float acc[4][4] = {};

    for (int k0 = 0; k0 < K; k0 += BK) {
        #pragma unroll
        for (int half = 0; half < 2; ++half) {
            int r = ar + half * 32;
            int grow = block_row + r;
            float4 v = make_float4(0.f, 0.f, 0.f, 0.f);
            if (grow < M) v = *(const float4*)&A[(size_t)grow * K + k0 + ac];
            As[ac + 0][r] = v.x; As[ac + 1][r] = v.y;
            As[ac + 2][r] = v.z; As[ac + 3][r] = v.w;
        }
        #pragma unroll
        for (int half = 0; half < 2; ++half) {
            int kk = bkr + half * 16;
            float4 v = *(const float4*)&B[(size_t)(k0 + kk) * N + block_col + bc];
            *(float4*)&Bs[kk][bc] = v;
        }
        __syncthreads();
        #pragma unroll
        for (int k = 0; k < BK; ++k) {
            float4 a = *(const float4*)&As[k][tr * 4];
            float4 b = *(const float4*)&Bs[k][tc * 4];
            float av[4] = {a.x, a.y, a.z, a.w};
            float bv[4] = {b.x, b.y, b.z, b.w};
            #pragma unroll
            for (int i = 0; i < 4; ++i)
                #pragma unroll
                for (int j = 0; j < 4; ++j)
                    acc[i][j] += av[i] * bv[j];
        }
        __syncthreads();
    }
    #pragma unroll
    for (int i = 0; i < 4; ++i) {
        int grow = block_row + tr * 4 + i;
        if (grow < M) {
            float4 o = make_float4(acc[i][0], acc[i][1], acc[i][2], acc[i][3]);
            if (bias) {
                int col = block_col + tc * 4;
                o.x += bias[col + 0]; o.y += bias[col + 1];
                o.z += bias[col + 2]; o.w += bias[col + 3];
            }
            *(float4*)&C[(size_t)grow * N + block_col + tc * 4] = o;
        }
    }
}

// conv[d][:] = dinv[d]*( sum_{s in in(d)} dinv[s]*h[s][:] + dinv[d]*h[d][:] ) + b_conv
// 32 lanes per node (float4 -> 128 cols), 8 nodes per 256-thread block. No atomics.
__global__ __launch_bounds__(256) void gather_kernel(
    const float* __restrict__ h, const int* __restrict__ row_ptr,
    const int* __restrict__ csr_src, const float* __restrict__ dinv,
    const float* __restrict__ b_conv, float* __restrict__ conv, int n)
{
    int group = threadIdx.x >> 5;
    int lane = threadIdx.x & 31;
    int d = blockIdx.x * 8 + group;
    if (d >= n) return;
    int c = lane << 2;
    float di = dinv[d];
    float4 hs = *(const float4*)&h[(size_t)d * HID + c];
    float4 acc = make_float4(di * hs.x, di * hs.y, di * hs.z, di * hs.w);  // self-loop term
    int begin = row_ptr[d], end = row_ptr[d + 1];
    for (int e = begin; e < end; ++e) {
        int s = csr_src[e];
        float w = dinv[s];
        float4 hv = *(const float4*)&h[(size_t)s * HID + c];
        acc.x += w * hv.x; acc.y += w * hv.y;
        acc.z += w * hv.z; acc.w += w * hv.w;
    }
    float4 bb = *(const float4*)&b_conv[c];
    float4 o = make_float4(di * acc.x + bb.x, di * acc.y + bb.y,
                           di * acc.z + bb.z, di * acc.w + bb.w);
    *(float4*)&conv[(size_t)d * HID + c] = o;
}

extern "C" void kernel_launch(void* const* d_in, const int* in_sizes, int n_in,
                              void* d_out, int out_size, void* d_ws, size_t ws_size,
                              hipStream_t stream) {
    const float* x      = (const float*)d_in[0];   // [50000,256]
    const int*   ei     = (const int*)d_in[1];     // [2,800000]
    const float* W_conv = (const float*)d_in[2];   // [256,128]
    const float* b_conv = (const float*)d_in[3];   // [128]
    const float* W_lin  = (const float*)d_in[4];   // [128,256]
    const float* b_lin  = (const float*)d_in[5];   // [256]
    float* out = (float*)d_out;                    // [50000,256]

    char* ws = (char*)d_ws;
    float* h       = (float*)(ws + OFF_H);
    float* conv    = (float*)(ws + OFF_CONV);
    int*   deg     = (int*)(ws + OFF_DEG);
    int*   cnt     = (int*)(ws + OFF_CNT);
    int*   row_ptr = (int*)(ws + OFF_RP);
    float* dinv    = (float*)(ws + OFF_DINV);
    int*   csr_src = (int*)(ws + OFF_CSR);

    const int* src = ei;             // edge_index[0]
    const int* dst = ei + N_EDGES;   // edge_index[1]

    // zero deg + cnt (contiguous 400,000 bytes)
    hipMemsetAsync(deg, 0, 400000, stream);

    deg_kernel<<<(N_EDGES + 255) / 256, 256, 0, stream>>>(dst, deg, N_EDGES);
    scan_kernel<<<1, 1024, 0, stream>>>(deg, row_ptr, N_NODES);
    dinv_kernel<<<(N_NODES + 255) / 256, 256, 0, stream>>>(row_ptr, dinv, N_NODES);
    bucket_kernel<<<(N_EDGES + 255) / 256, 256, 0, stream>>>(src, dst, row_ptr, cnt, csr_src, N_EDGES);

    dim3 g1((N_NODES + BM - 1) / BM, HID / BN);
    sgemm_kernel<<<g1, 256, 0, stream>>>(x, W_conv, nullptr, h, N_NODES, HID, IN_C);

    gather_kernel<<<(N_NODES + 7) / 8, 256, 0, stream>>>(h, row_ptr, csr_src, dinv, b_conv, conv, N_NODES);

    dim3 g2((N_NODES + BM - 1) / BM, IN_C / BN);
    sgemm_kernel<<<g2, 256, 0, stream>>>(conv, W_lin, b_lin, out, N_NODES, IN_C, HID);
}

// Round 2
// 345.342 us; speedup vs baseline: 1.2026x; 1.2026x over previous
//
#include <hip/hip_runtime.h>

// GCN layer: h = x @ W_conv; conv = D^-1/2 (A+I) D^-1/2 h + b_conv; out = conv @ W_lin + b_lin
// N=50000, E=800000, in_c=256, hid=128. All fp32.

#define N_NODES 50000
#define N_EDGES 800000
#define IN_C 256
#define HID 128
#define SCAN_BLOCKS ((N_NODES + 255) / 256)   // 196

// workspace layout (bytes)
#define OFF_H    0UL          // 50000*128 f32 = 25,600,000
#define OFF_CONV 25600000UL   // 50000*128 f32 = 25,600,000
#define OFF_DEG  51200000UL   // 50000 i32
#define OFF_CNT  51400000UL   // 50000 i32
#define OFF_RP   51600000UL   // 50001 i32
#define OFF_DINV 51800064UL   // 50000 f32
#define OFF_CSR  52000064UL   // 800000 i32
#define OFF_BSUM 55200064UL   // 256 i32 (ends 55,201,088)

__global__ void deg_kernel(const int* __restrict__ dst, int* __restrict__ deg, int e) {
    int i = blockIdx.x * blockDim.x + threadIdx.x;
    if (i < e) atomicAdd(&deg[dst[i]], 1);
}

// phase 1: block-local exclusive scan (256 elems/block), emit block sums
__global__ __launch_bounds__(256) void scan_blocks_kernel(
    const int* __restrict__ deg, int* __restrict__ row_ptr,
    int* __restrict__ bsums, int n)
{
    __shared__ int tmp[256];
    int tid = threadIdx.x;
    int i = blockIdx.x * 256 + tid;
    int v = (i < n) ? deg[i] : 0;
    int orig = v;
    tmp[tid] = v;
    __syncthreads();
    #pragma unroll
    for (int off = 1; off < 256; off <<= 1) {
        int t = (tid >= off) ? tmp[tid - off] : 0;
        __syncthreads();
        tmp[tid] += t;
        __syncthreads();
    }
    if (i < n) row_ptr[i] = tmp[tid] - orig;          // block-local exclusive
    if (tid == 255) bsums[blockIdx.x] = tmp[255];     // block total
}

// phase 2: one small block scans the block sums (nb=196 <= 256) to exclusive offsets
__global__ __launch_bounds__(256) void scan_sums_kernel(int* __restrict__ bsums, int nb) {
    __shared__ int tmp[256];
    int tid = threadIdx.x;
    int v = (tid < nb) ? bsums[tid] : 0;
    int orig = v;
    tmp[tid] = v;
    __syncthreads();
    #pragma unroll
    for (int off = 1; off < 256; off <<= 1) {
        int t = (tid >= off) ? tmp[tid - off] : 0;
        __syncthreads();
        tmp[tid] += t;
        __syncthreads();
    }
    if (tid < nb) bsums[tid] = tmp[tid] - orig;       // exclusive offsets
}

// phase 3: add block offsets; fuse dinv (= rsqrt(deg+1)); write row_ptr[n] (= E, constant)
__global__ __launch_bounds__(256) void finalize_kernel(
    const int* __restrict__ deg, int* __restrict__ row_ptr,
    const int* __restrict__ bsums, float* __restrict__ dinv, int n)
{
    int i = blockIdx.x * 256 + threadIdx.x;
    if (i < n) {
        row_ptr[i] += bsums[blockIdx.x];
        dinv[i] = rsqrtf((float)(deg[i] + 1));        // +1 self-loop
    }
    if (i == 0) row_ptr[n] = N_EDGES;                 // all dst < n, total is constant
}

__global__ void bucket_kernel(const int* __restrict__ src, const int* __restrict__ dst,
                              const int* __restrict__ row_ptr, int* __restrict__ cnt,
                              int* __restrict__ csr_src, int e) {
    int i = blockIdx.x * blockDim.x + threadIdx.x;
    if (i < e) {
        int d = dst[i];
        int slot = row_ptr[d] + atomicAdd(&cnt[d], 1);
        csr_src[slot] = src[i];
    }
}

// C[M,N] = A[M,K] @ B[K,N] (+bias). BM=64,BN=64,BK=32; 256 thr, 4x4/thread.
#define BM 64
#define BN 64
#define BK 32
__global__ __launch_bounds__(256) void sgemm_kernel(
    const float* __restrict__ A, const float* __restrict__ B,
    const float* __restrict__ bias, float* __restrict__ C,
    int M, int N, int K)
{
    __shared__ float As[BK][BM + 4];
    __shared__ float Bs[BK][BN];
    int tid = threadIdx.x;
    int block_row = blockIdx.x * BM;
    int block_col = blockIdx.y * BN;
    int tr = tid >> 4;
    int tc = tid & 15;
    int ar = tid >> 3;
    int ac = (tid & 7) << 2;
    int bkr = tid >> 4;
    int bc = (tid & 15) << 2;
    float acc[4][4] = {};

    for (int k0 = 0; k0 < K; k0 += BK) {
        #pragma unroll
        for (int half = 0; half < 2; ++half) {
            int r = ar + half * 32;
            int grow = block_row + r;
            float4 v = make_float4(0.f, 0.f, 0.f, 0.f);
            if (grow < M) v = *(const float4*)&A[(size_t)grow * K + k0 + ac];
            As[ac + 0][r] = v.x; As[ac + 1][r] = v.y;
            As[ac + 2][r] = v.z; As[ac + 3][r] = v.w;
        }
        #pragma unroll
        for (int half = 0; half < 2; ++half) {
            int kk = bkr + half * 16;
            float4 v = *(const float4*)&B[(size_t)(k0 + kk) * N + block_col + bc];
            *(float4*)&Bs[kk][bc] = v;
        }
        __syncthreads();
        #pragma unroll
        for (int k = 0; k < BK; ++k) {
            float4 a = *(const float4*)&As[k][tr * 4];
            float4 b = *(const float4*)&Bs[k][tc * 4];
            float av[4] = {a.x, a.y, a.z, a.w};
            float bv[4] = {b.x, b.y, b.z, b.w};
            #pragma unroll
            for (int i = 0; i < 4; ++i)
                #pragma unroll
                for (int j = 0; j < 4; ++j)
                    acc[i][j] += av[i] * bv[j];
        }
        __syncthreads();
    }
    #pragma unroll
    for (int i = 0; i < 4; ++i) {
        int grow = block_row + tr * 4 + i;
        if (grow < M) {
            float4 o = make_float4(acc[i][0], acc[i][1], acc[i][2], acc[i][3]);
            if (bias) {
                int col = block_col + tc * 4;
                o.x += bias[col + 0]; o.y += bias[col + 1];
                o.z += bias[col + 2]; o.w += bias[col + 3];
            }
            *(float4*)&C[(size_t)grow * N + block_col + tc * 4] = o;
        }
    }
}

// conv[d][:] = dinv[d]*( sum_{s in in(d)} dinv[s]*h[s][:] + dinv[d]*h[d][:] ) + b_conv
__global__ __launch_bounds__(256) void gather_kernel(
    const float* __restrict__ h, const int* __restrict__ row_ptr,
    const int* __restrict__ csr_src, const float* __restrict__ dinv,
    const float* __restrict__ b_conv, float* __restrict__ conv, int n)
{
    int group = threadIdx.x >> 5;
    int lane = threadIdx.x & 31;
    int d = blockIdx.x * 8 + group;
    if (d >= n) return;
    int c = lane << 2;
    float di = dinv[d];
    float4 hs = *(const float4*)&h[(size_t)d * HID + c];
    float4 acc = make_float4(di * hs.x, di * hs.y, di * hs.z, di * hs.w);
    int begin = row_ptr[d], end = row_ptr[d + 1];
    for (int e = begin; e < end; ++e) {
        int s = csr_src[e];
        float w = dinv[s];
        float4 hv = *(const float4*)&h[(size_t)s * HID + c];
        acc.x += w * hv.x; acc.y += w * hv.y;
        acc.z += w * hv.z; acc.w += w * hv.w;
    }
    float4 bb = *(const float4*)&b_conv[c];
    float4 o = make_float4(di * acc.x + bb.x, di * acc.y + bb.y,
                           di * acc.z + bb.z, di * acc.w + bb.w);
    *(float4*)&conv[(size_t)d * HID + c] = o;
}

extern "C" void kernel_launch(void* const* d_in, const int* in_sizes, int n_in,
                              void* d_out, int out_size, void* d_ws, size_t ws_size,
                              hipStream_t stream) {
    const float* x      = (const float*)d_in[0];
    const int*   ei     = (const int*)d_in[1];
    const float* W_conv = (const float*)d_in[2];
    const float* b_conv = (const float*)d_in[3];
    const float* W_lin  = (const float*)d_in[4];
    const float* b_lin  = (const float*)d_in[5];
    float* out = (float*)d_out;

    char* ws = (char*)d_ws;
    float* h       = (float*)(ws + OFF_H);
    float* conv    = (float*)(ws + OFF_CONV);
    int*   deg     = (int*)(ws + OFF_DEG);
    int*   cnt     = (int*)(ws + OFF_CNT);
    int*   row_ptr = (int*)(ws + OFF_RP);
    float* dinv    = (float*)(ws + OFF_DINV);
    int*   csr_src = (int*)(ws + OFF_CSR);
    int*   bsums   = (int*)(ws + OFF_BSUM);

    const int* src = ei;
    const int* dst = ei + N_EDGES;

    hipMemsetAsync(deg, 0, 400000, stream);  // deg + cnt contiguous

    deg_kernel<<<(N_EDGES + 255) / 256, 256, 0, stream>>>(dst, deg, N_EDGES);
    scan_blocks_kernel<<<SCAN_BLOCKS, 256, 0, stream>>>(deg, row_ptr, bsums, N_NODES);
    scan_sums_kernel<<<1, 256, 0, stream>>>(bsums, SCAN_BLOCKS);
    finalize_kernel<<<SCAN_BLOCKS, 256, 0, stream>>>(deg, row_ptr, bsums, dinv, N_NODES);
    bucket_kernel<<<(N_EDGES + 255) / 256, 256, 0, stream>>>(src, dst, row_ptr, cnt, csr_src, N_EDGES);

    dim3 g1((N_NODES + BM - 1) / BM, HID / BN);
    sgemm_kernel<<<g1, 256, 0, stream>>>(x, W_conv, nullptr, h, N_NODES, HID, IN_C);

    gather_kernel<<<(N_NODES + 7) / 8, 256, 0, stream>>>(h, row_ptr, csr_src, dinv, b_conv, conv, N_NODES);

    dim3 g2((N_NODES + BM - 1) / BM, IN_C / BN);
    sgemm_kernel<<<g2, 256, 0, stream>>>(conv, W_lin, b_lin, out, N_NODES, IN_C, HID);
}

// Round 3
// 334.997 us; speedup vs baseline: 1.2397x; 1.0309x over previous
//
#include <hip/hip_runtime.h>

// GCN layer: h = x @ W_conv; conv = D^-1/2 (A+I) D^-1/2 h + b_conv; out = conv @ W_lin + b_lin
// N=50000, E=800000, in_c=256, hid=128.
// h is materialized in bf16 only (gather traffic = 256 B/edge instead of 512 B).

#define N_NODES 50000
#define N_EDGES 800000
#define IN_C 256
#define HID 128
#define SCAN_BLOCKS ((N_NODES + 255) / 256)   // 196

// workspace layout (bytes)
#define OFF_H    0UL          // 50000*128 bf16 = 12,800,000
#define OFF_CONV 12800000UL   // 50000*128 f32  = 25,600,000
#define OFF_DEG  38400000UL   // 50000 i32
#define OFF_CNT  38600000UL   // 50000 i32
#define OFF_RP   38800000UL   // 50001 i32
#define OFF_DINV 39000064UL   // 50000 f32
#define OFF_CSR  39200064UL   // 800000 i32
#define OFF_BSUM 42400064UL   // 256 i32

__device__ __forceinline__ ushort f2bf(float x) {
    unsigned u = __float_as_uint(x);
    u += 0x7fffu + ((u >> 16) & 1u);       // round-to-nearest-even
    return (ushort)(u >> 16);
}

__global__ void deg_kernel(const int* __restrict__ dst, int* __restrict__ deg, int e) {
    int i = blockIdx.x * blockDim.x + threadIdx.x;
    if (i < e) atomicAdd(&deg[dst[i]], 1);
}

__global__ __launch_bounds__(256) void scan_blocks_kernel(
    const int* __restrict__ deg, int* __restrict__ row_ptr,
    int* __restrict__ bsums, int n)
{
    __shared__ int tmp[256];
    int tid = threadIdx.x;
    int i = blockIdx.x * 256 + tid;
    int v = (i < n) ? deg[i] : 0;
    int orig = v;
    tmp[tid] = v;
    __syncthreads();
    #pragma unroll
    for (int off = 1; off < 256; off <<= 1) {
        int t = (tid >= off) ? tmp[tid - off] : 0;
        __syncthreads();
        tmp[tid] += t;
        __syncthreads();
    }
    if (i < n) row_ptr[i] = tmp[tid] - orig;
    if (tid == 255) bsums[blockIdx.x] = tmp[255];
}

__global__ __launch_bounds__(256) void scan_sums_kernel(int* __restrict__ bsums, int nb) {
    __shared__ int tmp[256];
    int tid = threadIdx.x;
    int v = (tid < nb) ? bsums[tid] : 0;
    int orig = v;
    tmp[tid] = v;
    __syncthreads();
    #pragma unroll
    for (int off = 1; off < 256; off <<= 1) {
        int t = (tid >= off) ? tmp[tid - off] : 0;
        __syncthreads();
        tmp[tid] += t;
        __syncthreads();
    }
    if (tid < nb) bsums[tid] = tmp[tid] - orig;
}

__global__ __launch_bounds__(256) void finalize_kernel(
    const int* __restrict__ deg, int* __restrict__ row_ptr,
    const int* __restrict__ bsums, float* __restrict__ dinv, int n)
{
    int i = blockIdx.x * 256 + threadIdx.x;
    if (i < n) {
        row_ptr[i] += bsums[blockIdx.x];
        dinv[i] = rsqrtf((float)(deg[i] + 1));
    }
    if (i == 0) row_ptr[n] = N_EDGES;
}

__global__ void bucket_kernel(const int* __restrict__ src, const int* __restrict__ dst,
                              const int* __restrict__ row_ptr, int* __restrict__ cnt,
                              int* __restrict__ csr_src, int e) {
    int i = blockIdx.x * blockDim.x + threadIdx.x;
    if (i < e) {
        int d = dst[i];
        int slot = row_ptr[d] + atomicAdd(&cnt[d], 1);
        csr_src[slot] = src[i];
    }
}

// C[M,N] = A[M,K] @ B[K,N] (+bias). BM=64,BN=64,BK=32; 256 thr, 4x4/thread.
// BF16OUT: pack result rows to bf16 (ushort) instead of fp32.
#define BM 64
#define BN 64
#define BK 32
template <bool BF16OUT>
__global__ __launch_bounds__(256) void sgemm_kernel(
    const float* __restrict__ A, const float* __restrict__ B,
    const float* __restrict__ bias, void* __restrict__ Cv,
    int M, int N, int K)
{
    __shared__ float As[BK][BM + 4];
    __shared__ float Bs[BK][BN];
    int tid = threadIdx.x;
    int block_row = blockIdx.x * BM;
    int block_col = blockIdx.y * BN;
    int tr = tid >> 4;
    int tc = tid & 15;
    int ar = tid >> 3;
    int ac = (tid & 7) << 2;
    int bkr = tid >> 4;
    int bc = (tid & 15) << 2;
    float acc[4][4] = {};

    for (int k0 = 0; k0 < K; k0 += BK) {
        #pragma unroll
        for (int half = 0; half < 2; ++half) {
            int r = ar + half * 32;
            int grow = block_row + r;
            float4 v = make_float4(0.f, 0.f, 0.f, 0.f);
            if (grow < M) v = *(const float4*)&A[(size_t)grow * K + k0 + ac];
            As[ac + 0][r] = v.x; As[ac + 1][r] = v.y;
            As[ac + 2][r] = v.z; As[ac + 3][r] = v.w;
        }
        #pragma unroll
        for (int half = 0; half < 2; ++half) {
            int kk = bkr + half * 16;
            float4 v = *(const float4*)&B[(size_t)(k0 + kk) * N + block_col + bc];
            *(float4*)&Bs[kk][bc] = v;
        }
        __syncthreads();
        #pragma unroll
        for (int k = 0; k < BK; ++k) {
            float4 a = *(const float4*)&As[k][tr * 4];
            float4 b = *(const float4*)&Bs[k][tc * 4];
            float av[4] = {a.x, a.y, a.z, a.w};
            float bv[4] = {b.x, b.y, b.z, b.w};
            #pragma unroll
            for (int i = 0; i < 4; ++i)
                #pragma unroll
                for (int j = 0; j < 4; ++j)
                    acc[i][j] += av[i] * bv[j];
        }
        __syncthreads();
    }
    #pragma unroll
    for (int i = 0; i < 4; ++i) {
        int grow = block_row + tr * 4 + i;
        if (grow < M) {
            int col = block_col + tc * 4;
            float4 o = make_float4(acc[i][0], acc[i][1], acc[i][2], acc[i][3]);
            if (bias) {
                o.x += bias[col + 0]; o.y += bias[col + 1];
                o.z += bias[col + 2]; o.w += bias[col + 3];
            }
            if (BF16OUT) {
                ushort4 p;
                p.x = f2bf(o.x); p.y = f2bf(o.y); p.z = f2bf(o.z); p.w = f2bf(o.w);
                *(ushort4*)&((ushort*)Cv)[(size_t)grow * N + col] = p;
            } else {
                *(float4*)&((float*)Cv)[(size_t)grow * N + col] = o;
            }
        }
    }
}

// conv[d][:] = dinv[d]*( sum_{s in in(d)} dinv[s]*h[s][:] + dinv[d]*h[d][:] ) + b_conv
// one wave64 per node; h in bf16: each lane owns 2 cols (one 4B packed load per edge).
__global__ __launch_bounds__(256) void gather_kernel(
    const ushort* __restrict__ hb, const int* __restrict__ row_ptr,
    const int* __restrict__ csr_src, const float* __restrict__ dinv,
    const float* __restrict__ b_conv, float* __restrict__ conv, int n)
{
    int wave = threadIdx.x >> 6;
    int lane = threadIdx.x & 63;
    int d = blockIdx.x * 4 + wave;
    if (d >= n) return;
    int c = lane << 1;          // 2 cols per lane
    float di = dinv[d];
    unsigned hv = *(const unsigned*)&hb[(size_t)d * HID + c];
    float2 acc;
    acc.x = di * __uint_as_float(hv << 16);
    acc.y = di * __uint_as_float(hv & 0xffff0000u);
    int begin = row_ptr[d], end = row_ptr[d + 1];
    int e = begin;
    for (; e + 2 <= end; e += 2) {
        int s0 = csr_src[e];
        int s1 = csr_src[e + 1];
        float w0 = dinv[s0];
        float w1 = dinv[s1];
        unsigned v0 = *(const unsigned*)&hb[(size_t)s0 * HID + c];
        unsigned v1 = *(const unsigned*)&hb[(size_t)s1 * HID + c];
        acc.x += w0 * __uint_as_float(v0 << 16);
        acc.y += w0 * __uint_as_float(v0 & 0xffff0000u);
        acc.x += w1 * __uint_as_float(v1 << 16);
        acc.y += w1 * __uint_as_float(v1 & 0xffff0000u);
    }
    if (e < end) {
        int s0 = csr_src[e];
        float w0 = dinv[s0];
        unsigned v0 = *(const unsigned*)&hb[(size_t)s0 * HID + c];
        acc.x += w0 * __uint_as_float(v0 << 16);
        acc.y += w0 * __uint_as_float(v0 & 0xffff0000u);
    }
    float2 o;
    o.x = di * acc.x + b_conv[c];
    o.y = di * acc.y + b_conv[c + 1];
    *(float2*)&conv[(size_t)d * HID + c] = o;
}

extern "C" void kernel_launch(void* const* d_in, const int* in_sizes, int n_in,
                              void* d_out, int out_size, void* d_ws, size_t ws_size,
                              hipStream_t stream) {
    const float* x      = (const float*)d_in[0];
    const int*   ei     = (const int*)d_in[1];
    const float* W_conv = (const float*)d_in[2];
    const float* b_conv = (const float*)d_in[3];
    const float* W_lin  = (const float*)d_in[4];
    const float* b_lin  = (const float*)d_in[5];
    float* out = (float*)d_out;

    char* ws = (char*)d_ws;
    ushort* hb     = (ushort*)(ws + OFF_H);
    float* conv    = (float*)(ws + OFF_CONV);
    int*   deg     = (int*)(ws + OFF_DEG);
    int*   cnt     = (int*)(ws + OFF_CNT);
    int*   row_ptr = (int*)(ws + OFF_RP);
    float* dinv    = (float*)(ws + OFF_DINV);
    int*   csr_src = (int*)(ws + OFF_CSR);
    int*   bsums   = (int*)(ws + OFF_BSUM);

    const int* src = ei;
    const int* dst = ei + N_EDGES;

    hipMemsetAsync(deg, 0, 400000, stream);  // deg + cnt contiguous

    deg_kernel<<<(N_EDGES + 255) / 256, 256, 0, stream>>>(dst, deg, N_EDGES);
    scan_blocks_kernel<<<SCAN_BLOCKS, 256, 0, stream>>>(deg, row_ptr, bsums, N_NODES);
    scan_sums_kernel<<<1, 256, 0, stream>>>(bsums, SCAN_BLOCKS);
    finalize_kernel<<<SCAN_BLOCKS, 256, 0, stream>>>(deg, row_ptr, bsums, dinv, N_NODES);
    bucket_kernel<<<(N_EDGES + 255) / 256, 256, 0, stream>>>(src, dst, row_ptr, cnt, csr_src, N_EDGES);

    dim3 g1((N_NODES + BM - 1) / BM, HID / BN);
    sgemm_kernel<true><<<g1, 256, 0, stream>>>(x, W_conv, nullptr, hb, N_NODES, HID, IN_C);

    gather_kernel<<<(N_NODES + 3) / 4, 256, 0, stream>>>(hb, row_ptr, csr_src, dinv, b_conv, conv, N_NODES);

    dim3 g2((N_NODES + BM - 1) / BM, IN_C / BN);
    sgemm_kernel<false><<<g2, 256, 0, stream>>>(conv, W_lin, b_lin, out, N_NODES, IN_C, HID);
}

// Round 4
// 279.378 us; speedup vs baseline: 1.4865x; 1.1991x over previous
//
#include <hip/hip_runtime.h>

// GCN layer: h = x @ W_conv; conv = D^-1/2 (A+I) D^-1/2 h + b_conv; out = conv @ W_lin + b_lin
// N=50000, E=800000, in_c=256, hid=128.
// h and conv materialized in bf16; GEMMs use bf16 MFMA 16x16x32 (fp32 accumulate).

#define N_NODES 50000
#define N_EDGES 800000
#define IN_C 256
#define HID 128
#define SCAN_BLOCKS ((N_NODES + 255) / 256)   // 196
#define GEMM_MBLK ((N_NODES + 63) / 64)       // 782

// workspace layout (bytes)
#define OFF_H    0UL          // 50000*128 bf16 = 12,800,000
#define OFF_CONV 12800000UL   // 50000*128 bf16 = 12,800,000
#define OFF_DEG  25600000UL   // 50000 i32
#define OFF_CNT  25800000UL   // 50000 i32
#define OFF_RP   26000000UL   // 50001 i32
#define OFF_DINV 26200064UL   // 50000 f32
#define OFF_CSR  26400064UL   // 800000 i32 (ends 29,600,064)
#define OFF_BSUM 29600064UL   // 256 i32
#define OFF_WT1  29601088UL   // 128*256 bf16 = 65,536  (W_conv^T)
#define OFF_WT2  29666624UL   // 256*128 bf16 = 65,536  (W_lin^T)

typedef __attribute__((ext_vector_type(8))) short bf16x8;
typedef __attribute__((ext_vector_type(4))) float f32x4;

__device__ __forceinline__ ushort f2bf(float x) {
    unsigned u = __float_as_uint(x);
    u += 0x7fffu + ((u >> 16) & 1u);       // round-to-nearest-even
    return (ushort)(u >> 16);
}

__global__ void deg_kernel(const int* __restrict__ dst, int* __restrict__ deg, int e) {
    int i = blockIdx.x * blockDim.x + threadIdx.x;
    if (i < e) atomicAdd(&deg[dst[i]], 1);
}

__global__ __launch_bounds__(256) void scan_blocks_kernel(
    const int* __restrict__ deg, int* __restrict__ row_ptr,
    int* __restrict__ bsums, int n)
{
    __shared__ int tmp[256];
    int tid = threadIdx.x;
    int i = blockIdx.x * 256 + tid;
    int v = (i < n) ? deg[i] : 0;
    int orig = v;
    tmp[tid] = v;
    __syncthreads();
    #pragma unroll
    for (int off = 1; off < 256; off <<= 1) {
        int t = (tid >= off) ? tmp[tid - off] : 0;
        __syncthreads();
        tmp[tid] += t;
        __syncthreads();
    }
    if (i < n) row_ptr[i] = tmp[tid] - orig;
    if (tid == 255) bsums[blockIdx.x] = tmp[255];
}

__global__ __launch_bounds__(256) void scan_sums_kernel(int* __restrict__ bsums, int nb) {
    __shared__ int tmp[256];
    int tid = threadIdx.x;
    int v = (tid < nb) ? bsums[tid] : 0;
    int orig = v;
    tmp[tid] = v;
    __syncthreads();
    #pragma unroll
    for (int off = 1; off < 256; off <<= 1) {
        int t = (tid >= off) ? tmp[tid - off] : 0;
        __syncthreads();
        tmp[tid] += t;
        __syncthreads();
    }
    if (tid < nb) bsums[tid] = tmp[tid] - orig;
}

__global__ __launch_bounds__(256) void finalize_kernel(
    const int* __restrict__ deg, int* __restrict__ row_ptr,
    const int* __restrict__ bsums, float* __restrict__ dinv, int n)
{
    int i = blockIdx.x * 256 + threadIdx.x;
    if (i < n) {
        row_ptr[i] += bsums[blockIdx.x];
        dinv[i] = rsqrtf((float)(deg[i] + 1));
    }
    if (i == 0) row_ptr[n] = N_EDGES;
}

__global__ void bucket_kernel(const int* __restrict__ src, const int* __restrict__ dst,
                              const int* __restrict__ row_ptr, int* __restrict__ cnt,
                              int* __restrict__ csr_src, int e) {
    int i = blockIdx.x * blockDim.x + threadIdx.x;
    if (i < e) {
        int d = dst[i];
        int slot = row_ptr[d] + atomicAdd(&cnt[d], 1);
        csr_src[slot] = src[i];
    }
}

// W [K][N] fp32 -> Wt [N][K] bf16
__global__ void transpose_w_kernel(const float* __restrict__ W, ushort* __restrict__ Wt,
                                   int K, int N) {
    int i = blockIdx.x * 256 + threadIdx.x;
    if (i < N * K) {
        int n = i / K, k = i % K;
        Wt[i] = f2bf(W[k * N + n]);
    }
}

// C[M,N] = A[M,K] @ B[K,N] (+bias) via bf16 MFMA 16x16x32, fp32 accumulate.
// A row-major (fp32 or bf16); Bt = B^T bf16 row-major [N][K].
// BM=64, BN=128, BK=32; 256 threads = 4 waves in 2x2; wave tile 32x64 (2x4 MFMA tiles).
template <bool A_IS_BF16, bool BF16OUT>
__global__ __launch_bounds__(256) void mfma_gemm_kernel(
    const void* __restrict__ Av, const ushort* __restrict__ Bt,
    const float* __restrict__ bias, void* __restrict__ Cv,
    int M, int N, int K)
{
    constexpr int LDK = 40;   // 32 + 8 bf16 pad (16B-aligned rows)
    __shared__ ushort As[64 * LDK];
    __shared__ ushort Bs[128 * LDK];
    int tid = threadIdx.x;
    int wave = tid >> 6, lane = tid & 63;
    int quad = lane >> 4, l16 = lane & 15;
    int wm0 = (wave >> 1) * 32, wn0 = (wave & 1) * 64;
    int bm = blockIdx.x * 64, bn = blockIdx.y * 128;

    f32x4 acc[2][4] = {};

    for (int k0 = 0; k0 < K; k0 += 32) {
        // ---- stage A tile (64 x 32) ----
        {
            int row = tid >> 2, col = (tid & 3) * 8;
            int grow = bm + row;
            if (A_IS_BF16) {
                bf16x8 v = {};
                if (grow < M)
                    v = *(const bf16x8*)((const ushort*)Av + (size_t)grow * K + k0 + col);
                *(bf16x8*)&As[row * LDK + col] = v;
            } else {
                float4 v0 = make_float4(0.f, 0.f, 0.f, 0.f);
                float4 v1 = make_float4(0.f, 0.f, 0.f, 0.f);
                if (grow < M) {
                    const float* ap = (const float*)Av + (size_t)grow * K + k0 + col;
                    v0 = *(const float4*)ap;
                    v1 = *(const float4*)(ap + 4);
                }
                ushort t[8] = {f2bf(v0.x), f2bf(v0.y), f2bf(v0.z), f2bf(v0.w),
                               f2bf(v1.x), f2bf(v1.y), f2bf(v1.z), f2bf(v1.w)};
                *(bf16x8*)&As[row * LDK + col] = *(bf16x8*)t;
            }
        }
        // ---- stage B tile (128 x 32) from Bt rows (contiguous k) ----
        {
            int ch = tid * 2;
            int n = ch >> 2;              // 4 chunks of 8 per row
            int kk = (ch & 3) * 8;
            const ushort* bp = Bt + (size_t)(bn + n) * K + k0 + kk;
            *(bf16x8*)&Bs[n * LDK + kk]     = *(const bf16x8*)bp;
            *(bf16x8*)&Bs[n * LDK + kk + 8] = *(const bf16x8*)(bp + 8);
        }
        __syncthreads();
        bf16x8 af[2], bfr[4];
        #pragma unroll
        for (int im = 0; im < 2; ++im)
            af[im] = *(bf16x8*)&As[(wm0 + im * 16 + l16) * LDK + quad * 8];
        #pragma unroll
        for (int in = 0; in < 4; ++in)
            bfr[in] = *(bf16x8*)&Bs[(wn0 + in * 16 + l16) * LDK + quad * 8];
        #pragma unroll
        for (int im = 0; im < 2; ++im)
            #pragma unroll
            for (int in = 0; in < 4; ++in)
                acc[im][in] = __builtin_amdgcn_mfma_f32_16x16x32_bf16(
                    af[im], bfr[in], acc[im][in], 0, 0, 0);
        __syncthreads();
    }
    // ---- epilogue: C/D layout col=lane&15, row=quad*4+reg ----
    #pragma unroll
    for (int im = 0; im < 2; ++im) {
        #pragma unroll
        for (int in = 0; in < 4; ++in) {
            int col = bn + wn0 + in * 16 + l16;
            float bval = bias ? bias[col] : 0.f;
            #pragma unroll
            for (int r = 0; r < 4; ++r) {
                int grow = bm + wm0 + im * 16 + quad * 4 + r;
                if (grow < M) {
                    float o = acc[im][in][r] + bval;
                    if (BF16OUT)
                        ((ushort*)Cv)[(size_t)grow * N + col] = f2bf(o);
                    else
                        ((float*)Cv)[(size_t)grow * N + col] = o;
                }
            }
        }
    }
}

// convb[d][:] = bf16( dinv[d]*( sum_in dinv[s]*h[s][:] + dinv[d]*h[d][:] ) + b_conv )
// one wave64 per node; h bf16: lane owns 2 cols (4B packed load per edge).
__global__ __launch_bounds__(256) void gather_kernel(
    const ushort* __restrict__ hb, const int* __restrict__ row_ptr,
    const int* __restrict__ csr_src, const float* __restrict__ dinv,
    const float* __restrict__ b_conv, ushort* __restrict__ convb, int n)
{
    int wave = threadIdx.x >> 6;
    int lane = threadIdx.x & 63;
    int d = blockIdx.x * 4 + wave;
    if (d >= n) return;
    int c = lane << 1;
    float di = dinv[d];
    unsigned hv = *(const unsigned*)&hb[(size_t)d * HID + c];
    float2 acc;
    acc.x = di * __uint_as_float(hv << 16);
    acc.y = di * __uint_as_float(hv & 0xffff0000u);
    int begin = row_ptr[d], end = row_ptr[d + 1];
    int e = begin;
    for (; e + 2 <= end; e += 2) {
        int s0 = csr_src[e];
        int s1 = csr_src[e + 1];
        float w0 = dinv[s0];
        float w1 = dinv[s1];
        unsigned v0 = *(const unsigned*)&hb[(size_t)s0 * HID + c];
        unsigned v1 = *(const unsigned*)&hb[(size_t)s1 * HID + c];
        acc.x += w0 * __uint_as_float(v0 << 16);
        acc.y += w0 * __uint_as_float(v0 & 0xffff0000u);
        acc.x += w1 * __uint_as_float(v1 << 16);
        acc.y += w1 * __uint_as_float(v1 & 0xffff0000u);
    }
    if (e < end) {
        int s0 = csr_src[e];
        float w0 = dinv[s0];
        unsigned v0 = *(const unsigned*)&hb[(size_t)s0 * HID + c];
        acc.x += w0 * __uint_as_float(v0 << 16);
        acc.y += w0 * __uint_as_float(v0 & 0xffff0000u);
    }
    float ox = di * acc.x + b_conv[c];
    float oy = di * acc.y + b_conv[c + 1];
    unsigned po = ((unsigned)f2bf(oy) << 16) | (unsigned)f2bf(ox);
    *(unsigned*)&convb[(size_t)d * HID + c] = po;
}

extern "C" void kernel_launch(void* const* d_in, const int* in_sizes, int n_in,
                              void* d_out, int out_size, void* d_ws, size_t ws_size,
                              hipStream_t stream) {
    const float* x      = (const float*)d_in[0];
    const int*   ei     = (const int*)d_in[1];
    const float* W_conv = (const float*)d_in[2];
    const float* b_conv = (const float*)d_in[3];
    const float* W_lin  = (const float*)d_in[4];
    const float* b_lin  = (const float*)d_in[5];
    float* out = (float*)d_out;

    char* ws = (char*)d_ws;
    ushort* hb     = (ushort*)(ws + OFF_H);
    ushort* convb  = (ushort*)(ws + OFF_CONV);
    int*   deg     = (int*)(ws + OFF_DEG);
    int*   cnt     = (int*)(ws + OFF_CNT);
    int*   row_ptr = (int*)(ws + OFF_RP);
    float* dinv    = (float*)(ws + OFF_DINV);
    int*   csr_src = (int*)(ws + OFF_CSR);
    int*   bsums   = (int*)(ws + OFF_BSUM);
    ushort* wt_conv = (ushort*)(ws + OFF_WT1);
    ushort* wt_lin  = (ushort*)(ws + OFF_WT2);

    const int* src = ei;
    const int* dst = ei + N_EDGES;

    hipMemsetAsync(deg, 0, 400000, stream);  // deg + cnt contiguous

    deg_kernel<<<(N_EDGES + 255) / 256, 256, 0, stream>>>(dst, deg, N_EDGES);
    scan_blocks_kernel<<<SCAN_BLOCKS, 256, 0, stream>>>(deg, row_ptr, bsums, N_NODES);
    scan_sums_kernel<<<1, 256, 0, stream>>>(bsums, SCAN_BLOCKS);
    finalize_kernel<<<SCAN_BLOCKS, 256, 0, stream>>>(deg, row_ptr, bsums, dinv, N_NODES);
    bucket_kernel<<<(N_EDGES + 255) / 256, 256, 0, stream>>>(src, dst, row_ptr, cnt, csr_src, N_EDGES);

    transpose_w_kernel<<<(HID * IN_C + 255) / 256, 256, 0, stream>>>(W_conv, wt_conv, IN_C, HID);
    transpose_w_kernel<<<(IN_C * HID + 255) / 256, 256, 0, stream>>>(W_lin, wt_lin, HID, IN_C);

    // h = bf16(x @ W_conv)
    mfma_gemm_kernel<false, true><<<dim3(GEMM_MBLK, HID / 128), 256, 0, stream>>>(
        x, wt_conv, nullptr, hb, N_NODES, HID, IN_C);

    gather_kernel<<<(N_NODES + 3) / 4, 256, 0, stream>>>(
        hb, row_ptr, csr_src, dinv, b_conv, convb, N_NODES);

    // out = conv @ W_lin + b_lin
    mfma_gemm_kernel<true, false><<<dim3(GEMM_MBLK, IN_C / 128), 256, 0, stream>>>(
        convb, wt_lin, b_lin, out, N_NODES, IN_C, HID);
}